// Round 5
// baseline (361.118 us; speedup 1.0000x reference)
//
#include <hip/hip_runtime.h>
#include <hip/hip_bf16.h>

typedef __bf16 bf16_t;
typedef __bf16 bf16x8 __attribute__((ext_vector_type(8)));
typedef __bf16 bf16x4 __attribute__((ext_vector_type(4)));
typedef float f32x4 __attribute__((ext_vector_type(4)));
typedef float f32x16 __attribute__((ext_vector_type(16)));

#define BS 4
#define SL 2048
#define DM 1024
#define NH 16
#define HD 64
#define QSCALE 0.18033688f   /* 0.125 * log2(e) */

static __device__ __forceinline__ bf16_t tobf(float x) { return (bf16_t)x; }

#if __has_builtin(__builtin_amdgcn_exp2f)
#define EXP2(x) __builtin_amdgcn_exp2f(x)
#else
#define EXP2(x) exp2f(x)
#endif

#if __has_builtin(__builtin_amdgcn_cvt_pk_bf16_f32)
typedef __bf16 bf16x2_t __attribute__((ext_vector_type(2)));
static __device__ __forceinline__ uint32_t pack_bf16(float a, float b) {
  union { bf16x2_t v; uint32_t u; } c;
  c.v = __builtin_amdgcn_cvt_pk_bf16_f32(a, b);
  return c.u;
}
#else
static __device__ __forceinline__ uint32_t pack_bf16(float a, float b) {
  union { bf16_t e[2]; uint32_t u; } c;
  c.e[0] = tobf(a); c.e[1] = tobf(b);
  return c.u;
}
#endif

// async global->LDS, 16B per lane; dest = lds_base + lane*16 (wave-uniform base)
static __device__ __forceinline__ void glds16(const void* g, void* l) {
  __builtin_amdgcn_global_load_lds(
      (const __attribute__((address_space(1))) void*)g,
      (__attribute__((address_space(3))) void*)l, 16, 0, 0);
}

// ---------------------------------------------------------------------------
// Convert: 3 activations [8192x1024] + 4 weights [1024x1024] fp32 -> bf16.
// Grid (8192, 7); weight rows early-exit past 1024 blocks.
// ---------------------------------------------------------------------------
__global__ void convert_kernel(
    const float* __restrict__ q, const float* __restrict__ k, const float* __restrict__ v,
    const float* __restrict__ wq, const float* __restrict__ wk,
    const float* __restrict__ wv, const float* __restrict__ wo,
    bf16_t* __restrict__ aq, bf16_t* __restrict__ ak, bf16_t* __restrict__ av,
    bf16_t* __restrict__ wcat, bf16_t* __restrict__ wob)
{
  const float* s; bf16_t* d; int n;
  switch (blockIdx.y) {
    case 0: s = q;  d = aq;   n = BS * SL * DM; break;
    case 1: s = k;  d = ak;   n = BS * SL * DM; break;
    case 2: s = v;  d = av;   n = BS * SL * DM; break;
    case 3: s = wq; d = wcat;              n = DM * DM; break;
    case 4: s = wk; d = wcat + DM * DM;    n = DM * DM; break;
    case 5: s = wv; d = wcat + 2 * DM * DM; n = DM * DM; break;
    default: s = wo; d = wob;              n = DM * DM; break;
  }
  int i = (blockIdx.x * 256 + threadIdx.x) * 4;
  if (i >= n) return;
  float4 x = *(const float4*)(s + i);
  bf16x4 o; o[0] = tobf(x.x); o[1] = tobf(x.y); o[2] = tobf(x.z); o[3] = tobf(x.w);
  *(bf16x4*)(d + i) = o;
}

// ---------------------------------------------------------------------------
// Fused QKV GEMM, all-bf16, double-buffered single-barrier K-loop.
// C_p = A_p[8192,1024] * W_p^T + b_p,  p = blockIdx.y>>3 in {Q,K,V}.
// Tile 128x128, BK=32, 16KB/buf dbuf -> 4 blocks/CU.
// Q epilogue folds softmax scale; V epilogue writes transposed Vt.
// ---------------------------------------------------------------------------
__global__ __launch_bounds__(256, 4) void gemm_qkv_kernel(
    const bf16_t* __restrict__ Aq, const bf16_t* __restrict__ Ak, const bf16_t* __restrict__ Avv,
    const bf16_t* __restrict__ Wcat,
    const float* __restrict__ bq, const float* __restrict__ bk, const float* __restrict__ bvv,
    bf16_t* __restrict__ Qb, bf16_t* __restrict__ Kbo, bf16_t* __restrict__ Vtb)
{
  __shared__ __align__(16) char sMem[32768];   // [A0 8K][B0 8K][A1 8K][B1 8K]

  const int proj = blockIdx.y >> 3;
  const bf16_t* Af  = proj == 0 ? Aq : (proj == 1 ? Ak : Avv);
  const float* bias = proj == 0 ? bq : (proj == 1 ? bk : bvv);

  const int tid  = threadIdx.x;
  const int wave = tid >> 6;
  const int lane = tid & 63;
  const int l15  = lane & 15;
  const int quad = lane >> 4;
  const int m0 = blockIdx.x * 128;
  const int nW = blockIdx.y * 128;           // row base in Wcat
  const int n0 = (blockIdx.y & 7) * 128;     // col base in dest
  const int wm = (wave & 1) * 64;
  const int wn = (wave >> 1) * 64;

  auto stage = [&](int r, int k0) {
    char* base = sMem + r * 16384;
#pragma unroll
    for (int t = 0; t < 2; t++) {
      int slot = wave * 2 + t;
      int f = slot * 64 + lane;
      int row = f >> 2;
      int cg = (f & 3) ^ (row & 3);
      glds16(Af   + (size_t)(m0 + row) * DM + k0 + cg * 8, base + slot * 1024);
      glds16(Wcat + (size_t)(nW + row) * DM + k0 + cg * 8, base + 8192 + slot * 1024);
    }
  };

  f32x4 acc[4][4];
#pragma unroll
  for (int i = 0; i < 4; i++)
#pragma unroll
    for (int j = 0; j < 4; j++) acc[i][j] = f32x4{0.f, 0.f, 0.f, 0.f};

  stage(0, 0);
  for (int t = 0; t < 32; ++t) {
    __syncthreads();                         // stage(t) landed; old buf reads done
    if (t < 31) stage((t + 1) & 1, (t + 1) * 32);

    const bf16_t* sA = (const bf16_t*)(sMem + (t & 1) * 16384);
    const bf16_t* sB = sA + 4096;

    bf16x8 af[4], bfr[4];
#pragma unroll
    for (int i = 0; i < 4; i++) {
      int row = wm + i * 16 + l15;
      af[i] = *(const bf16x8*)(sA + row * 32 + (quad ^ (row & 3)) * 8);
    }
#pragma unroll
    for (int j = 0; j < 4; j++) {
      int row = wn + j * 16 + l15;
      bfr[j] = *(const bf16x8*)(sB + row * 32 + (quad ^ (row & 3)) * 8);
    }

#pragma unroll
    for (int i = 0; i < 4; i++)
#pragma unroll
      for (int j = 0; j < 4; j++)
        acc[i][j] = __builtin_amdgcn_mfma_f32_16x16x32_bf16(af[i], bfr[j], acc[i][j], 0, 0, 0);
  }

  if (proj == 0) {
    // Q: scale by QSCALE after bias (folds softmax scale + log2e)
#pragma unroll
    for (int j = 0; j < 4; j++) {
      int col = n0 + wn + j * 16 + l15;
      float bv = bias[col];
#pragma unroll
      for (int i = 0; i < 4; i++) {
        int rowb = m0 + wm + i * 16 + quad * 4;
#pragma unroll
        for (int r = 0; r < 4; r++)
          Qb[(size_t)(rowb + r) * DM + col] = tobf((acc[i][j][r] + bv) * QSCALE);
      }
    }
  } else if (proj == 1) {
#pragma unroll
    for (int j = 0; j < 4; j++) {
      int col = n0 + wn + j * 16 + l15;
      float bv = bias[col];
#pragma unroll
      for (int i = 0; i < 4; i++) {
        int rowb = m0 + wm + i * 16 + quad * 4;
#pragma unroll
        for (int r = 0; r < 4; r++)
          Kbo[(size_t)(rowb + r) * DM + col] = tobf(acc[i][j][r] + bv);
      }
    }
  } else {
    // V: write transposed Vt[(b*NH+head)*HD+hd][s], 4 consecutive s per lane
#pragma unroll
    for (int j = 0; j < 4; j++) {
      int col = n0 + wn + j * 16 + l15;
      float bv = bias[col];
      int head = col >> 6, hd = col & 63;
#pragma unroll
      for (int i = 0; i < 4; i++) {
        int rowb = m0 + wm + i * 16 + quad * 4;
        int b = rowb >> 11, s = rowb & (SL - 1);
        bf16x4 o;
#pragma unroll
        for (int r = 0; r < 4; r++) o[r] = tobf(acc[i][j][r] + bv);
        *(bf16x4*)(Vtb + ((size_t)(b * NH + head) * HD + hd) * SL + s) = o;
      }
    }
  }
}

// ---------------------------------------------------------------------------
// Output GEMM: C[8192,1024] fp32 = A bf16 * Wo^T + bo.
// Tile 128x64 (grid 64x16 = 1024 blocks = 4/CU), BK=32, dbuf 24KB.
// ---------------------------------------------------------------------------
__global__ __launch_bounds__(256, 4) void gemm_out_kernel(
    const bf16_t* __restrict__ A, const bf16_t* __restrict__ Bw,
    const float* __restrict__ bias, float* __restrict__ C)
{
  __shared__ __align__(16) char sMem[24576];   // [A0 8K][B0 4K][A1 8K][B1 4K]

  const int tid  = threadIdx.x;
  const int wave = tid >> 6;
  const int lane = tid & 63;
  const int l15  = lane & 15;
  const int quad = lane >> 4;
  const int m0 = blockIdx.x * 128;
  const int n0 = blockIdx.y * 64;
  const int wm = (wave & 1) * 64;
  const int wn = (wave >> 1) * 32;

  auto stage = [&](int r, int k0) {
    char* base = sMem + r * 12288;
#pragma unroll
    for (int t = 0; t < 2; t++) {            // A: 512 chunks
      int slot = wave * 2 + t;
      int f = slot * 64 + lane;
      int row = f >> 2;
      int cg = (f & 3) ^ (row & 3);
      glds16(A + (size_t)(m0 + row) * DM + k0 + cg * 8, base + slot * 1024);
    }
    {                                         // B: 256 chunks (64 rows)
      int f = wave * 64 + lane;
      int row = f >> 2;
      int cg = (f & 3) ^ (row & 3);
      glds16(Bw + (size_t)(n0 + row) * DM + k0 + cg * 8, base + 8192 + wave * 1024);
    }
  };

  f32x4 acc[4][2];
#pragma unroll
  for (int i = 0; i < 4; i++)
#pragma unroll
    for (int j = 0; j < 2; j++) acc[i][j] = f32x4{0.f, 0.f, 0.f, 0.f};

  stage(0, 0);
  for (int t = 0; t < 32; ++t) {
    __syncthreads();
    if (t < 31) stage((t + 1) & 1, (t + 1) * 32);

    const bf16_t* sA = (const bf16_t*)(sMem + (t & 1) * 12288);
    const bf16_t* sB = sA + 4096;

    bf16x8 af[4], bfr[2];
#pragma unroll
    for (int i = 0; i < 4; i++) {
      int row = wm + i * 16 + l15;
      af[i] = *(const bf16x8*)(sA + row * 32 + (quad ^ (row & 3)) * 8);
    }
#pragma unroll
    for (int j = 0; j < 2; j++) {
      int row = wn + j * 16 + l15;
      bfr[j] = *(const bf16x8*)(sB + row * 32 + (quad ^ (row & 3)) * 8);
    }

#pragma unroll
    for (int i = 0; i < 4; i++)
#pragma unroll
      for (int j = 0; j < 2; j++)
        acc[i][j] = __builtin_amdgcn_mfma_f32_16x16x32_bf16(af[i], bfr[j], acc[i][j], 0, 0, 0);
  }

#pragma unroll
  for (int j = 0; j < 2; j++) {
    int col = n0 + wn + j * 16 + l15;
    float bv = bias[col];
#pragma unroll
    for (int i = 0; i < 4; i++) {
      int rowb = m0 + wm + i * 16 + quad * 4;
#pragma unroll
      for (int r = 0; r < 4; r++)
        C[(size_t)(rowb + r) * DM + col] = acc[i][j][r] + bv;
    }
  }
}

// ---------------------------------------------------------------------------
// Flash attention, S^T form, LDS-staged K/V (glds), double-buffered,
// ONE barrier per 64-key tile. 32x32x16 MFMA; fixed-shift exp2 softmax
// (C-init = -12*log2e; Q pre-scaled at projection). P^T via register shuffles.
// ---------------------------------------------------------------------------
__global__ __launch_bounds__(256, 4) void attn_kernel(
    const bf16_t* __restrict__ Q, const bf16_t* __restrict__ Kb,
    const bf16_t* __restrict__ Vt, bf16_t* __restrict__ O)
{
  __shared__ __align__(16) char sMem[32768];   // [K0 8K][V0 8K][K1 8K][V1 8K]

  const int tid  = threadIdx.x;
  const int wave = tid >> 6;
  const int lane = tid & 63;
  const int l31  = lane & 31;
  const int h    = lane >> 5;
  const int swl  = l31 & 7;

  const int id  = blockIdx.x;            // 1024 blocks
  const int xcd = id & 7, slot = id >> 3;
  const int bh  = xcd * 8 + (slot >> 4); // 8 bh per XCD -> K/V L2-resident
  const int qi  = slot & 15;
  const int b = bh >> 4, hh = bh & 15;
  const int q0 = qi * 128 + wave * 32;

  auto stage = [&](int r, int k0) {
    char* base = sMem + r * 16384;
#pragma unroll
    for (int t = 0; t < 2; t++) {
      int slot2 = wave * 2 + t;
      int f = slot2 * 64 + lane;
      int row = f >> 3;
      int cg = (f & 7) ^ ((row + (row >> 3)) & 7);
      glds16(Kb + (size_t)(b * SL + k0 + row) * DM + hh * HD + cg * 8,
             base + slot2 * 1024);
      glds16(Vt + ((size_t)bh * HD + row) * SL + k0 + cg * 8,
             base + 8192 + slot2 * 1024);
    }
  };

  // Q B-frags: n=q=l31, k=hd = c*16 + h*8 + j (pre-scaled at projection)
  bf16x8 qf[4];
  {
    const bf16_t* qp = Q + (size_t)(b * SL + q0 + l31) * DM + hh * HD + h * 8;
#pragma unroll
    for (int c = 0; c < 4; c++) qf[c] = *(const bf16x8*)(qp + c * 16);
  }

  f32x16 o_acc[2];
#pragma unroll
  for (int m = 0; m < 2; m++)
#pragma unroll
    for (int r = 0; r < 16; r++) o_acc[m][r] = 0.f;
  float rs0 = 0.f, rs1 = 0.f;

  stage(0, 0);
  for (int t = 0; t < 32; ++t) {
    __syncthreads();                      // stage(t) landed; prev buf reads done
    if (t < 31) stage((t + 1) & 1, (t + 1) * 64);

    const bf16_t* sK = (const bf16_t*)(sMem + (t & 1) * 16384);
    const bf16_t* sV = sK + 4096;

#pragma unroll
    for (int s = 0; s < 2; s++) {
      // S^T[key][q]: A = K rows (key = s*32 + l31)
      int rowK = s * 32 + l31;
      int kkK = (rowK + (rowK >> 3)) & 7;
      bf16x8 kf[4];
#pragma unroll
      for (int c = 0; c < 4; c++)
        kf[c] = *(const bf16x8*)(sK + rowK * 64 + (((c * 2 + h) ^ kkK) * 8));

      f32x16 st;
#pragma unroll
      for (int r = 0; r < 16; r++) st[r] = -17.312340f;   // -12*log2(e)
#pragma unroll
      for (int c = 0; c < 4; c++)
        st = __builtin_amdgcn_mfma_f32_32x32x16_bf16(kf[c], qf[c], st, 0, 0, 0);

      // p = 2^st; row-sum; pack bf16 pairs (reg r = key (r&3)+8*(r>>2)+4h)
      uint32_t w[8];
#pragma unroll
      for (int i = 0; i < 8; i++) {
        float p0 = EXP2(st[2 * i]);
        float p1 = EXP2(st[2 * i + 1]);
        rs0 += p0; rs1 += p1;
        w[i] = pack_bf16(p0, p1);
      }
      // cross-half exchange -> P^T B-frags (layout verified R2/R3)
      uint32_t y0 = (uint32_t)__shfl_xor((int)(h ? w[0] : w[2]), 32);
      uint32_t y1 = (uint32_t)__shfl_xor((int)(h ? w[1] : w[3]), 32);
      uint32_t y2 = (uint32_t)__shfl_xor((int)(h ? w[4] : w[6]), 32);
      uint32_t y3 = (uint32_t)__shfl_xor((int)(h ? w[5] : w[7]), 32);
      union { uint32_t u[4]; bf16x8 v; } pf0, pf1;
      pf0.u[0] = h ? y0   : w[0];
      pf0.u[1] = h ? y1   : w[1];
      pf0.u[2] = h ? w[2] : y0;
      pf0.u[3] = h ? w[3] : y1;
      pf1.u[0] = h ? y2   : w[4];
      pf1.u[1] = h ? y3   : w[5];
      pf1.u[2] = h ? w[6] : y2;
      pf1.u[3] = h ? w[7] : y3;

      // O^T[hd][q] += V^T[hd][key] * P^T
#pragma unroll
      for (int m = 0; m < 2; m++) {
        int rowV = m * 32 + l31;
        int kkV = (rowV + (rowV >> 3)) & 7;
#pragma unroll
        for (int c = 0; c < 2; c++) {
          int chunk = (s * 4 + c * 2 + h) ^ kkV;
          bf16x8 vf = *(const bf16x8*)(sV + rowV * 64 + chunk * 8);
          o_acc[m] = __builtin_amdgcn_mfma_f32_32x32x16_bf16(
              vf, (c ? pf1.v : pf0.v), o_acc[m], 0, 0, 0);
        }
      }
    }
  }

  // epilogue: normalize, transpose O^T->O via per-wave LDS (region 0 free:
  // last tile t=31 used region 1)
  float rs = rs0 + rs1;
  rs += __shfl_xor(rs, 32);
  float inv = 1.f / rs;
  bf16_t* so = (bf16_t*)sMem + wave * 2048;   // 32q x 64hd, 4KB per wave
#pragma unroll
  for (int m = 0; m < 2; m++) {
#pragma unroll
    for (int r = 0; r < 16; r++) {
      int hd = m * 32 + (r & 3) + 8 * (r >> 2) + 4 * h;
      so[l31 * 64 + (((hd >> 3) ^ swl) * 8) + (hd & 7)] = tobf(o_acc[m][r] * inv);
    }
  }
  asm volatile("s_waitcnt lgkmcnt(0)" ::: "memory");   // wave-private region
  {
    int qr = lane >> 1, hf = lane & 1;
    int sw2 = qr & 7;
#pragma unroll
    for (int cc = 0; cc < 4; cc++) {
      int chunk = (hf * 4 + cc) ^ sw2;
      bf16x8 v = *(const bf16x8*)(so + qr * 64 + chunk * 8);
      *(bf16x8*)(O + (size_t)(b * SL + q0 + qr) * DM + hh * HD + hf * 32 + cc * 8) = v;
    }
  }
}

// ---------------------------------------------------------------------------
extern "C" void kernel_launch(void* const* d_in, const int* in_sizes, int n_in,
                              void* d_out, int out_size, void* d_ws, size_t ws_size,
                              hipStream_t stream)
{
  const float* value  = (const float*)d_in[0];
  const float* key_in = (const float*)d_in[1];
  const float* query  = (const float*)d_in[2];
  const float* Wq = (const float*)d_in[3];
  const float* bq = (const float*)d_in[4];
  const float* Wk = (const float*)d_in[5];
  const float* bk = (const float*)d_in[6];
  const float* Wv = (const float*)d_in[7];
  const float* bv = (const float*)d_in[8];
  const float* Wo = (const float*)d_in[9];
  const float* bo = (const float*)d_in[10];

  char* ws = (char*)d_ws;
  const size_t sz  = (size_t)BS * SL * DM * sizeof(bf16_t);  // 16.78 MB
  const size_t wsz = (size_t)DM * DM * sizeof(bf16_t);       // 2 MB
  bf16_t* Aqb  = (bf16_t*)(ws + 0 * sz);
  bf16_t* Akb  = (bf16_t*)(ws + 1 * sz);
  bf16_t* Avb  = (bf16_t*)(ws + 2 * sz);
  bf16_t* Qb   = (bf16_t*)(ws + 3 * sz);
  bf16_t* Kb   = (bf16_t*)(ws + 4 * sz);
  bf16_t* Vtb  = (bf16_t*)(ws + 5 * sz);
  bf16_t* Wcat = (bf16_t*)(ws + 6 * sz);                     // [3072][1024]
  bf16_t* Wob  = (bf16_t*)(ws + 6 * sz + 3 * wsz);
  bf16_t* Ob   = Aqb;   // Aq activation dead after qkv GEMM

  const int M = BS * SL;  // 8192

  convert_kernel<<<dim3(M * DM / 1024, 7), 256, 0, stream>>>(
      query, key_in, value, Wq, Wk, Wv, Wo, Aqb, Akb, Avb, Wcat, Wob);

  gemm_qkv_kernel<<<dim3(M / 128, 24), 256, 0, stream>>>(
      Aqb, Akb, Avb, Wcat, bq, bk, bv, Qb, Kb, Vtb);

  attn_kernel<<<dim3(SL / 128 * BS * NH), 256, 0, stream>>>(Qb, Kb, Vtb, Ob);

  gemm_out_kernel<<<dim3(M / 128, DM / 64), 256, 0, stream>>>(Ob, Wob, bo, (float*)d_out);
}